// Round 3
// baseline (149.648 us; speedup 1.0000x reference)
//
#include <hip/hip_runtime.h>
#include <hip/hip_bf16.h>

#define M 8192
#define N 8192
#define K 512
#define BM 256
#define BN 256
#define BK 64
#define NT (K / BK)  // 8 K-tiles
#define EPSV 1e-8f

typedef __attribute__((ext_vector_type(8))) short bf16x8;
typedef __attribute__((ext_vector_type(4))) float f32x4;
typedef __attribute__((ext_vector_type(8))) unsigned short us8;

__device__ inline void gload_lds16(const void* g, void* l) {
  __builtin_amdgcn_global_load_lds(
      (const __attribute__((address_space(1))) unsigned int*)g,
      (__attribute__((address_space(3))) unsigned int*)l, 16, 0, 0);
}

#define BARRIER()                          \
  do {                                     \
    asm volatile("" ::: "memory");         \
    __builtin_amdgcn_s_barrier();          \
    asm volatile("" ::: "memory");         \
  } while (0)

// Fused prep: blocks [0,2048) cast img -> Abf + w1; [2048,4096) txt -> Bbf + w2.
__global__ __launch_bounds__(256) void prep_kernel(const float* __restrict__ img,
                                                   const float* __restrict__ txt,
                                                   unsigned short* __restrict__ Abf,
                                                   unsigned short* __restrict__ Bbf,
                                                   float* __restrict__ w1,
                                                   float* __restrict__ w2) {
  const int half = blockIdx.x >> 11;  // 0: img, 1: txt
  const int lb = blockIdx.x & 2047;
  const float* in = half ? txt : img;
  unsigned short* outb = half ? Bbf : Abf;
  float* norms = half ? w2 : w1;

  const int gw = (lb * 256 + threadIdx.x) >> 6;
  const int lane = threadIdx.x & 63;
  const float4* rp4 = (const float4*)(in + (size_t)gw * K);
  float4 v0 = rp4[lane * 2];
  float4 v1 = rp4[lane * 2 + 1];
  float ss = v0.x * v0.x + v0.y * v0.y + v0.z * v0.z + v0.w * v0.w +
             v1.x * v1.x + v1.y * v1.y + v1.z * v1.z + v1.w * v1.w;
  float f[8] = {v0.x, v0.y, v0.z, v0.w, v1.x, v1.y, v1.z, v1.w};
  us8 o;
#pragma unroll
  for (int i = 0; i < 8; ++i) {
    __hip_bfloat16 b = __float2bfloat16(f[i]);
    o[i] = *(unsigned short*)&b;
  }
  *(us8*)(outb + (size_t)gw * K + lane * 8) = o;
#pragma unroll
  for (int off = 32; off > 0; off >>= 1) ss += __shfl_down(ss, off, 64);
  if (lane == 0) norms[gw] = sqrtf(ss);
}

// 256x256 8-phase bf16 GEMM: C[i][j] = <A_i,B_j>/max(w1*w2,eps)
__global__ __launch_bounds__(512, 2) void gemm_kernel(const unsigned short* __restrict__ A,
                                                      const unsigned short* __restrict__ B,
                                                      const float* __restrict__ w1,
                                                      const float* __restrict__ w2,
                                                      float* __restrict__ C) {
  __shared__ __align__(128) unsigned short As[2][2][128 * 64];
  __shared__ __align__(128) unsigned short Bs[2][2][128 * 64];

  const int tid = threadIdx.x;
  const int wave = tid >> 6;
  const int lane = tid & 63;
  const int wr = wave >> 2;  // 0..1 : wave M-half
  const int wc = wave & 3;   // 0..3 : wave N-quarter (64 cols)
  const int fr = lane & 15;
  const int fq = lane >> 4;

  // Two-level swizzle: xcd = bid&7 owns col-panels [xcd*4, xcd*4+4);
  // idx>>2 walks row-panels, idx&3 walks the XCD's 4 col-panels.
  // Concurrent working set per XCD: 8 A-panels (2MB) + 4 B-panels (1MB) <= L2.
  const int xcd = blockIdx.x & 7;
  const int idx = blockIdx.x >> 3;  // 0..127
  const int bRow = (idx >> 2) * BM;
  const int bCol = (xcd * 4 + (idx & 3)) * BN;

  // Staging: half-tile = 128 rows x 128 B; linear LDS dest, source col
  // pre-swizzled with involution byte^=((row&7)<<4) (rule #21).
  const int r0 = tid >> 3;
  const int r1 = 64 + (tid >> 3);
  const int csw = ((tid & 7) * 16) ^ ((r0 & 7) << 4);

  auto stageA = [&](int buf, int half, int kt) {
    gload_lds16(A + (size_t)(bRow + half * 128 + r0) * K + kt * BK + (csw >> 1),
                (char*)&As[buf][half][0] + wave * 1024);
    gload_lds16(A + (size_t)(bRow + half * 128 + r1) * K + kt * BK + (csw >> 1),
                (char*)&As[buf][half][0] + 8192 + wave * 1024);
  };
  auto stageB = [&](int buf, int half, int kt) {
    gload_lds16(B + (size_t)(bCol + half * 128 + r0) * K + kt * BK + (csw >> 1),
                (char*)&Bs[buf][half][0] + wave * 1024);
    gload_lds16(B + (size_t)(bCol + half * 128 + r1) * K + kt * BK + (csw >> 1),
                (char*)&Bs[buf][half][0] + 8192 + wave * 1024);
  };
  auto ldA = [&](int buf, int r, int cb) -> bf16x8 {
    return *(const bf16x8*)((const char*)&As[buf][wr][0] + r * 128 + (cb ^ ((r & 7) << 4)));
  };
  auto ldB = [&](int buf, int r, int cb) -> bf16x8 {
    return *(const bf16x8*)((const char*)&Bs[buf][wc >> 1][0] + r * 128 + (cb ^ ((r & 7) << 4)));
  };

  f32x4 acc[8][4] = {};
  bf16x8 a[4][2], bLo[2][2], bHi[2][2];
  const int bRowB = (wc & 1) * 64;

  // Prologue: tile0 A+B, tile1 B (12 loads); first 8 must land.
  stageA(0, 0, 0);
  stageA(0, 1, 0);
  stageB(0, 0, 0);
  stageB(0, 1, 0);
  stageB(1, 0, 1);
  stageB(1, 1, 1);
  asm volatile("s_waitcnt vmcnt(4)" ::: "memory");
  BARRIER();

#define MFMA_Q(MB, BARR, NB)                                                      \
  _Pragma("unroll") for (int kk = 0; kk < 2; ++kk)                                \
      _Pragma("unroll") for (int m = 0; m < 4; ++m)                               \
          _Pragma("unroll") for (int n = 0; n < 2; ++n)                           \
              acc[(MB) + m][(NB) + n] = __builtin_amdgcn_mfma_f32_16x16x32_bf16(  \
                  a[m][kk], BARR[n][kk], acc[(MB) + m][(NB) + n], 0, 0, 0);

#pragma unroll
  for (int t = 0; t < NT; ++t) {
    const int cur = t & 1, nxt = cur ^ 1;

    // ---- phase 1: ds_read A m0-3 + B n0-1 ; stage A half0 (t+1)
#pragma unroll
    for (int m = 0; m < 4; ++m)
#pragma unroll
      for (int kk = 0; kk < 2; ++kk) a[m][kk] = ldA(cur, m * 16 + fr, kk * 64 + fq * 16);
#pragma unroll
    for (int n = 0; n < 2; ++n)
#pragma unroll
      for (int kk = 0; kk < 2; ++kk)
        bLo[n][kk] = ldB(cur, bRowB + n * 16 + fr, kk * 64 + fq * 16);
    if (t + 1 < NT) stageA(nxt, 0, t + 1);
    BARRIER();
    __builtin_amdgcn_s_setprio(1);
    MFMA_Q(0, bLo, 0)
    __builtin_amdgcn_s_setprio(0);
    BARRIER();

    // ---- phase 2: ds_read B n2-3 ; stage A half1 (t+1)
#pragma unroll
    for (int n = 0; n < 2; ++n)
#pragma unroll
      for (int kk = 0; kk < 2; ++kk)
        bHi[n][kk] = ldB(cur, bRowB + 32 + n * 16 + fr, kk * 64 + fq * 16);
    if (t + 1 < NT) stageA(nxt, 1, t + 1);
    BARRIER();
    __builtin_amdgcn_s_setprio(1);
    MFMA_Q(0, bHi, 2)
    __builtin_amdgcn_s_setprio(0);
    BARRIER();

    // ---- phase 3: ds_read A m4-7 ; stage B half0 (t+2)
#pragma unroll
    for (int m = 0; m < 4; ++m)
#pragma unroll
      for (int kk = 0; kk < 2; ++kk) a[m][kk] = ldA(cur, 64 + m * 16 + fr, kk * 64 + fq * 16);
    if (t + 2 < NT) stageB(cur, 0, t + 2);
    BARRIER();
    __builtin_amdgcn_s_setprio(1);
    MFMA_Q(4, bLo, 0)
    __builtin_amdgcn_s_setprio(0);
    BARRIER();

    // ---- phase 4: stage B half1 (t+2) ; MFMA ; counted vmcnt ; barrier
    if (t + 2 < NT) stageB(cur, 1, t + 2);
    BARRIER();
    __builtin_amdgcn_s_setprio(1);
    MFMA_Q(4, bHi, 2)
    __builtin_amdgcn_s_setprio(0);
    if (t < NT - 2) {
      asm volatile("s_waitcnt vmcnt(4)" ::: "memory");
    } else if (t == NT - 2) {
      asm volatile("s_waitcnt vmcnt(0)" ::: "memory");
    }
    BARRIER();
  }
#undef MFMA_Q

  // Epilogue: C/D layout col = lane&15, row = (lane>>4)*4 + reg.
  // Nontemporal stores: keep the 256MB C stream out of L2/L3 so the
  // 16MB bf16 A/B panels stay cache-resident.
#pragma unroll
  for (int m = 0; m < 8; ++m) {
    const int row0 = bRow + wr * 128 + m * 16 + fq * 4;
    float w1v[4];
#pragma unroll
    for (int r = 0; r < 4; ++r) w1v[r] = w1[row0 + r];
#pragma unroll
    for (int n = 0; n < 4; ++n) {
      const int col = bCol + wc * 64 + n * 16 + fr;
      const float w2v = w2[col];
      f32x4 v = acc[m][n];
#pragma unroll
      for (int r = 0; r < 4; ++r)
        __builtin_nontemporal_store(v[r] / fmaxf(w1v[r] * w2v, EPSV),
                                    &C[(size_t)(row0 + r) * N + col]);
    }
  }
}

extern "C" void kernel_launch(void* const* d_in, const int* in_sizes, int n_in,
                              void* d_out, int out_size, void* d_ws, size_t ws_size,
                              hipStream_t stream) {
  (void)in_sizes; (void)n_in; (void)out_size; (void)ws_size;
  const float* img = (const float*)d_in[0];
  const float* txt = (const float*)d_in[1];
  float* out = (float*)d_out;

  unsigned short* Abf = (unsigned short*)d_ws;
  unsigned short* Bbf = Abf + (size_t)M * K;
  float* w1 = (float*)(Bbf + (size_t)N * K);
  float* w2 = w1 + M;

  prep_kernel<<<4096, 256, 0, stream>>>(img, txt, Abf, Bbf, w1, w2);
  gemm_kernel<<<(M / BM) * (N / BN), 512, 0, stream>>>(Abf, Bbf, w1, w2, out);
}

// Round 4
// 111.973 us; speedup vs baseline: 1.3365x; 1.3365x over previous
//
#include <hip/hip_runtime.h>
#include <hip/hip_bf16.h>

#define M 8192
#define N 8192
#define K 512
#define BM 256
#define BN 128
#define BK 32
#define NT (K / BK)  // 16 K-tiles
#define EPSV 1e-8f

typedef __attribute__((ext_vector_type(8))) short bf16x8;
typedef __attribute__((ext_vector_type(4))) float f32x4;
typedef __attribute__((ext_vector_type(8))) unsigned short us8;

__device__ inline void gload_lds16(const void* g, void* l) {
  __builtin_amdgcn_global_load_lds(
      (const __attribute__((address_space(1))) unsigned int*)g,
      (__attribute__((address_space(3))) unsigned int*)l, 16, 0, 0);
}

#define BARRIER()                          \
  do {                                     \
    asm volatile("" ::: "memory");         \
    __builtin_amdgcn_s_barrier();          \
    asm volatile("" ::: "memory");         \
  } while (0)

// Fused prep: blocks [0,2048) cast img -> Abf + w1; [2048,4096) txt -> Bbf + w2.
__global__ __launch_bounds__(256) void prep_kernel(const float* __restrict__ img,
                                                   const float* __restrict__ txt,
                                                   unsigned short* __restrict__ Abf,
                                                   unsigned short* __restrict__ Bbf,
                                                   float* __restrict__ w1,
                                                   float* __restrict__ w2) {
  const int half = blockIdx.x >> 11;
  const int lb = blockIdx.x & 2047;
  const float* in = half ? txt : img;
  unsigned short* outb = half ? Bbf : Abf;
  float* norms = half ? w2 : w1;

  const int gw = (lb * 256 + threadIdx.x) >> 6;
  const int lane = threadIdx.x & 63;
  const float4* rp4 = (const float4*)(in + (size_t)gw * K);
  float4 v0 = rp4[lane * 2];
  float4 v1 = rp4[lane * 2 + 1];
  float ss = v0.x * v0.x + v0.y * v0.y + v0.z * v0.z + v0.w * v0.w +
             v1.x * v1.x + v1.y * v1.y + v1.z * v1.z + v1.w * v1.w;
  float f[8] = {v0.x, v0.y, v0.z, v0.w, v1.x, v1.y, v1.z, v1.w};
  us8 o;
#pragma unroll
  for (int i = 0; i < 8; ++i) {
    __hip_bfloat16 b = __float2bfloat16(f[i]);
    o[i] = *(unsigned short*)&b;
  }
  *(us8*)(outb + (size_t)gw * K + lane * 8) = o;
#pragma unroll
  for (int off = 32; off > 0; off >>= 1) ss += __shfl_down(ss, off, 64);
  if (lane == 0) norms[gw] = sqrtf(ss);
}

// 256x128 bf16 GEMM, BK=32, 8 waves (wave tile 64x64), 2 blocks/CU.
// C[i][j] = <A_i,B_j>/max(w1[i]*w2[j], eps).
// LDS rows are 64B (BK=32 bf16): a wave's fragment ds_read covers 64 distinct
// contiguous 16B chunks -> conflict-free with NO swizzle; gload_lds dest linear.
__global__ __launch_bounds__(512, 4) void gemm_kernel(const unsigned short* __restrict__ A,
                                                      const unsigned short* __restrict__ B,
                                                      const float* __restrict__ w1,
                                                      const float* __restrict__ w2,
                                                      float* __restrict__ C) {
  __shared__ __align__(128) unsigned short As[2][BM * BK];  // 2 x 16 KB
  __shared__ __align__(128) unsigned short Bs[3][BN * BK];  // 3 x 8 KB

  const int tid = threadIdx.x;
  const int wave = tid >> 6;
  const int lane = tid & 63;
  const int wr = wave >> 1;  // 0..3 : M strip of 64
  const int wc = wave & 1;   // 0..1 : N strip of 64
  const int fr = lane & 15;
  const int fq = lane >> 4;

  // Two-level swizzle: xcd owns 8 col-panels; inner loop walks them, outer
  // walks row-panels -> per-XCD L2 working set ~1.25 MB, B strip L2-resident.
  const int xcd = blockIdx.x & 7;
  const int idx = blockIdx.x >> 3;            // 0..255
  const int bRow = (idx >> 3) * BM;           // 32 row-panels
  const int bCol = (xcd * 8 + (idx & 7)) * BN;  // 64 col-panels

  const int srow = lane >> 2;       // 0..15 row within wave's 16-row slab
  const int scol = (lane & 3) * 8;  // bf16 col offset

  auto stageA = [&](int buf, int kt) {
#pragma unroll
    for (int c = 0; c < 2; ++c)
      gload_lds16(A + (size_t)(bRow + c * 128 + wave * 16 + srow) * K + kt * BK + scol,
                  (char*)&As[buf][0] + (c * 128 + wave * 16) * 64);
  };
  auto stageB = [&](int buf, int kt) {
    gload_lds16(B + (size_t)(bCol + wave * 16 + srow) * K + kt * BK + scol,
                (char*)&Bs[buf][0] + wave * 16 * 64);
  };
  auto ldA = [&](int buf, int r) -> bf16x8 {
    return *(const bf16x8*)((const char*)&As[buf][0] + r * 64 + fq * 16);
  };
  auto ldB = [&](int buf, int r) -> bf16x8 {
    return *(const bf16x8*)((const char*)&Bs[buf][0] + r * 64 + fq * 16);
  };

  f32x4 acc[4][4] = {};
  bf16x8 a[4], b[4];

  // Prologue: A(0) [2 loads], B(0) [1], B(1) [1]; need A0,B0 landed.
  stageA(0, 0);
  stageB(0, 0);
  stageB(1, 1);
  asm volatile("s_waitcnt vmcnt(1)" ::: "memory");
  BARRIER();

#pragma unroll
  for (int t = 0; t < NT; ++t) {
    const int cur = t & 1, nxt = cur ^ 1;
    const int bc = t % 3, b2 = (t + 2) % 3;

    // ---- phase 1: ds_read a0-3, b0-1 ; stage A(t+1) ; MFMA m0-3 x n0-1
#pragma unroll
    for (int m = 0; m < 4; ++m) a[m] = ldA(cur, wr * 64 + m * 16 + fr);
    b[0] = ldB(bc, wc * 64 + fr);
    b[1] = ldB(bc, wc * 64 + 16 + fr);
    if (t + 1 < NT) stageA(nxt, t + 1);
    BARRIER();
    __builtin_amdgcn_s_setprio(1);
#pragma unroll
    for (int m = 0; m < 4; ++m)
#pragma unroll
      for (int n = 0; n < 2; ++n)
        acc[m][n] = __builtin_amdgcn_mfma_f32_16x16x32_bf16(a[m], b[n], acc[m][n], 0, 0, 0);
    __builtin_amdgcn_s_setprio(0);
    BARRIER();

    // ---- phase 2: ds_read b2-3 ; stage B(t+2) ; MFMA m0-3 x n2-3 ; counted vmcnt
    b[2] = ldB(bc, wc * 64 + 32 + fr);
    b[3] = ldB(bc, wc * 64 + 48 + fr);
    if (t + 2 < NT) stageB(b2, t + 2);
    BARRIER();
    __builtin_amdgcn_s_setprio(1);
#pragma unroll
    for (int m = 0; m < 4; ++m)
#pragma unroll
      for (int n = 2; n < 4; ++n)
        acc[m][n] = __builtin_amdgcn_mfma_f32_16x16x32_bf16(a[m], b[n], acc[m][n], 0, 0, 0);
    __builtin_amdgcn_s_setprio(0);
    if (t < NT - 2) {
      // FIFO: [B(t+1)][A(t+1)x2][B(t+2)] -> leave only B(t+2) in flight
      asm volatile("s_waitcnt vmcnt(1)" ::: "memory");
    } else if (t == NT - 2) {
      asm volatile("s_waitcnt vmcnt(0)" ::: "memory");
    }
    BARRIER();
  }

  // Epilogue: C/D layout col = lane&15, row = (lane>>4)*4 + reg. Plain stores
  // (L2 write-combining; NT stores caused RMW amplification in round 3).
#pragma unroll
  for (int m = 0; m < 4; ++m) {
    const int row0 = bRow + wr * 64 + m * 16 + fq * 4;
    float w1v[4];
#pragma unroll
    for (int r = 0; r < 4; ++r) w1v[r] = w1[row0 + r];
#pragma unroll
    for (int n = 0; n < 4; ++n) {
      const int col = bCol + wc * 64 + n * 16 + fr;
      const float w2v = w2[col];
      f32x4 v = acc[m][n];
#pragma unroll
      for (int r = 0; r < 4; ++r)
        C[(size_t)(row0 + r) * N + col] = v[r] / fmaxf(w1v[r] * w2v, EPSV);
    }
  }
}

extern "C" void kernel_launch(void* const* d_in, const int* in_sizes, int n_in,
                              void* d_out, int out_size, void* d_ws, size_t ws_size,
                              hipStream_t stream) {
  (void)in_sizes; (void)n_in; (void)out_size; (void)ws_size;
  const float* img = (const float*)d_in[0];
  const float* txt = (const float*)d_in[1];
  float* out = (float*)d_out;

  unsigned short* Abf = (unsigned short*)d_ws;
  unsigned short* Bbf = Abf + (size_t)M * K;
  float* w1 = (float*)(Bbf + (size_t)N * K);
  float* w2 = w1 + M;

  prep_kernel<<<4096, 256, 0, stream>>>(img, txt, Abf, Bbf, w1, w2);
  gemm_kernel<<<(M / BM) * (N / BN), 512, 0, stream>>>(Abf, Bbf, w1, w2, out);
}